// Round 15
// baseline (33.199 us; speedup 1.0000x reference)
//
#include <hip/hip_runtime.h>
#include <hip/hip_fp16.h>
#include <math.h>

// Radon forward, exact reference semantics (rotated-lattice bilinear gather).
//
// Round-21 changes vs round 20 (32.05 us champion; bbox table paid +1.2):
//  * Residual model: VALU ~10 us + LDS ~12 us vs wall ~28.6 -> ~5-6 us is
//    the 8 serial wave-local vmcnt(0) drains per wave (L2 latency exposed,
//    ~250-400 cyc each, only partly hidden at 8 waves/SIMD).
//  * 2-deep WAVE-PRIVATE double-buffer at IDENTICAL geometry (the clean
//    experiment r11/r14/r17 never ran -- those were confounded by block
//    convoys / barrier width / work inflation):
//      iter sub: lgkmcnt(0) -> stage(sub+1 -> buf^1) -> vmcnt(4) (drains
//      current buf only; next's 4 loads stay in flight) -> gather(sub).
//      vmcnt(0) only at the last subtile. Staged bytes, subtile count,
//      tap code byte-identical to r20.
//  * LDS: 4 waves x 2 bufs x 4 KB = 32,768 B exactly; separate red[]
//    deleted -- epilogue reuses each wave's own buf0 region (dead by then;
//    same-wave DS ordering + acc data-dependency make it safe) ->
//    5 blocks/CU x 4 waves = 20 waves/CU.
//  * Isolates ONE variable: pipeline depth (1->2) vs TLP (32->20 waves).

#define G       363
#define NT      180
#define PADB    53
#define STEP    (2.0f / 362.0f)
#define DEG2RAD 0.017453292519943295f

#define TSW     32          // tile row length (u32 cells)
#define NJB     12          // j-blocks of 32
#define NJBF    6           // fallback j-blocks of 64
#define CW      264         // canvas cols (4 guard + 256 + 4 guard)
#define CH      264         // canvas rows
#define NWSLOT  (NT * NJB * 2 * 2)     // 8640 wave slots
#define NTUPLE  (NWSLOT * 8)           // 69120 subtile origins

#define GLOAD16(gp, lp) __builtin_amdgcn_global_load_lds(                     \
    (const __attribute__((address_space(1))) void*)(gp),                      \
    (__attribute__((address_space(3))) void*)(lp), 16, 0, 0)

// ---------------- fallback gather kernel (known-good, round 1) -------------
__global__ __launch_bounds__(256) void radon_fwd(
    const float* __restrict__ x, const int* __restrict__ theta,
    float* __restrict__ out)
{
    const int t = blockIdx.x / NJBF, jb = blockIdx.x % NJBF;
    const int jl = threadIdx.x, chunk = threadIdx.y;
    const int j = jb * 64 + jl;
    const float th = (float)theta[t] * DEG2RAD;
    const float c = cosf(th), s = sinf(th);
    const float xj = fmaf((float)j, STEP, -1.0f);
    const float s181 = s * 181.0f, c181 = c * 181.0f;
    const float bx = fmaf(c, xj, 1.0f) * 181.0f;
    const float by = fmaf(-s, xj, 1.0f) * 181.0f;
    const float* img0 = x;
    const float* img1 = x + 65536;
    float acc0 = 0.f, acc1 = 0.f;
    for (int i = chunk; i < G; i += 4) {
        const float xi = fmaf((float)i, STEP, -1.0f);
        const float ix = fmaf(s181, xi, bx);
        const float iy = fmaf(c181, xi, by);
        const float fx = floorf(ix), fy = floorf(iy);
        const int ix0 = (int)fx, iy0 = (int)fy;
        const float wx1 = ix - fx, wy1 = iy - fy;
        const float wx0 = 1.f - wx1, wy0 = 1.f - wy1;
        const int cc0 = ix0 - 53, cc1 = cc0 + 1, rr0 = iy0 - 53, rr1 = rr0 + 1;
        const float wxa = ((unsigned)cc0 < 256u) ? wx0 : 0.f;
        const float wxb = ((unsigned)cc1 < 256u) ? wx1 : 0.f;
        const float wya = ((unsigned)rr0 < 256u) ? wy0 : 0.f;
        const float wyb = ((unsigned)rr1 < 256u) ? wy1 : 0.f;
        const int c0c = min(max(cc0, 0), 255), c1c = min(max(cc1, 0), 255);
        const int r0b = min(max(rr0, 0), 255) << 8, r1b = min(max(rr1, 0), 255) << 8;
        const float w00 = wya * wxa, w01 = wya * wxb, w10 = wyb * wxa, w11 = wyb * wxb;
        acc0 = fmaf(img0[r0b + c0c], w00, acc0);
        acc0 = fmaf(img0[r0b + c1c], w01, acc0);
        acc0 = fmaf(img0[r1b + c0c], w10, acc0);
        acc0 = fmaf(img0[r1b + c1c], w11, acc0);
        acc1 = fmaf(img1[r0b + c0c], w00, acc1);
        acc1 = fmaf(img1[r0b + c1c], w01, acc1);
        acc1 = fmaf(img1[r1b + c0c], w10, acc1);
        acc1 = fmaf(img1[r1b + c1c], w11, acc1);
    }
    __shared__ float red[2][4][64];
    red[0][chunk][jl] = acc0;
    red[1][chunk][jl] = acc1;
    __syncthreads();
    if (threadIdx.y < 2 && j < G) {
        const int n = threadIdx.y;
        out[n * (G * NT) + j * NT + t] =
            red[n][0][jl] + red[n][1][jl] + red[n][2][jl] + red[n][3][jl];
    }
}

// --------- prep: f16x2 canvases + per-(wave,sub) bbox-origin table ---------
// Blocks [0,81): canvases.  [81,351): bbox table (one tuple per thread).
__global__ __launch_bounds__(256) void prep_k(
    const float* __restrict__ x, const int* __restrict__ theta,
    unsigned* __restrict__ xIh, unsigned* __restrict__ xTIh,
    int2* __restrict__ bbox)
{
    const int bid = blockIdx.x;
    const int tx = threadIdx.x, ty = threadIdx.y;
    const int tid = ty * 32 + tx;

    if (bid < 81) {
        __shared__ unsigned tl[32][33];
        const int cx0 = (bid % 9) * 32, cy0 = (bid / 9) * 32;
        #pragma unroll
        for (int dy = 0; dy < 32; dy += 8) {
            const int cy = cy0 + ty + dy, cx = cx0 + tx;
            const int pr = cy - 4, pc = cx - 4;
            unsigned v = 0u;
            if ((unsigned)pr < 256u && (unsigned)pc < 256u) {
                const int p = pr * 256 + pc;
                const unsigned short a = __half_as_ushort(__float2half_rn(x[p]));
                const unsigned short b = __half_as_ushort(__float2half_rn(x[p + 65536]));
                v = (unsigned)a | ((unsigned)b << 16);
            }
            if (cy < CH && cx < CW) xIh[cy * CW + cx] = v;
            tl[ty + dy][tx] = v;
        }
        __syncthreads();
        #pragma unroll
        for (int dy = 0; dy < 32; dy += 8) {
            const int rp = cx0 + ty + dy, cp = cy0 + tx;
            if (rp < CH && cp < CW) xTIh[rp * CW + cp] = tl[tx][ty + dy];
        }
    } else {
        const int tuple = (bid - 81) * 256 + tid;
        if (tuple < NTUPLE) {
            // decode: (((t*NJB + jb)*2 + wj)*2 + wi)*8 + sub
            const int sub = tuple & 7;
            const int ws  = tuple >> 3;
            const int wi  = ws & 1;
            const int wj  = (ws >> 1) & 1;
            const int jb  = (ws >> 2) % NJB;
            const int t   = (ws >> 2) / NJB;

            // ---- identical fmaf chain to the main kernel ----
            const float th = (float)theta[t] * DEG2RAD;
            const float c = cosf(th), s = sinf(th);
            const float s181 = s * 181.0f, c181 = c * 181.0f;
            const int caseA = (fabsf(c) >= fabsf(s));
            const float slopeU = caseA ? c181 : s181;
            const float slopeV = caseA ? s181 : c181;
            const float dU = slopeU * STEP;
            const float dV = slopeV * STEP;

            const int   j0  = jb * 32 + wj * 16;
            const float xjm = fmaf((float)j0,        STEP, -1.0f);
            const float xjM = fmaf((float)(j0 + 15), STEP, -1.0f);
            const float bxm = fmaf(c,  xjm, 1.0f) * 181.0f;
            const float bym = fmaf(-s, xjm, 1.0f) * 181.0f;
            const float bxM = fmaf(c,  xjM, 1.0f) * 181.0f;
            const float byM = fmaf(-s, xjM, 1.0f) * 181.0f;
            const float U00m = (caseA ? bym : bxm) - slopeU;
            const float U00M = (caseA ? byM : bxM) - slopeU;
            const float V00m = (caseA ? bxm : bym) - slopeV;
            const float V00M = (caseA ? bxM : byM) - slopeV;

            const int i0 = (wi * 8 + sub) * 24;
            const float fi0 = (float)i0, fi1 = (float)(i0 + 23);
            const float Umin = fminf(fminf(fmaf(dU, fi0, U00m), fmaf(dU, fi0, U00M)),
                                     fminf(fmaf(dU, fi1, U00m), fmaf(dU, fi1, U00M)));
            const float Vmin = fminf(fminf(fmaf(dV, fi0, V00m), fmaf(dV, fi0, V00M)),
                                     fminf(fmaf(dV, fi1, V00m), fmaf(dV, fi1, V00M)));
            const int r0 = (int)floorf(Umin) - 1;
            const int c0 = (int)floorf(Vmin) - 1;
            bbox[tuple] = make_int2(r0, c0);
        }
    }
}

// ---------------- staging: 4x global_load_lds into one 4 KB buffer ---------
template<bool SAFE>
__device__ __forceinline__ void stage32(char* buf_b,
    const unsigned* __restrict__ srcC, int r0p, int c0p, int lane)
{
    const int ty0 = lane >> 3;             // 0..7
    const int tx  = (lane & 7) << 2;       // 0,4,...,28 (4 cells/lane)
    #pragma unroll
    for (int u = 0; u < 4; ++u) {
        const int ty = ty0 + (u << 3);
        int idx;
        if (SAFE) {
            idx = (r0p + 4 + ty) * CW + (c0p + 4 + tx);
        } else {
            // clamp into 4-wide zero guard: OOB taps read guaranteed zeros
            const int rc = min(max(r0p + ty, -4), 256) + 4;
            const int cc = min(max(c0p + tx, -4), 256) + 4;
            idx = rc * CW + cc;
        }
        GLOAD16(srcC + idx, buf_b + (u << 10));
    }
}

// ---------------- gather inner loop (6 i-steps, packed-f16 lerp) -----------
template<bool TAIL>
__device__ __forceinline__ void gather6(const unsigned* __restrict__ tl,
    float Uf0, float Vf0, float dU, float dV, int iexc,
    float& a0, float& a1)
{
    __half2 acc = __float2half2_rn(0.0f);
    #pragma unroll
    for (int k = 0; k < 6; ++k) {
        const float Uf = fmaf((float)k, dU, Uf0);   // independent, no chain
        const float Vf = fmaf((float)k, dV, Vf0);
        const float fU = floorf(Uf), fV = floorf(Vf);
        const float wU1 = Uf - fU;
        const float wV1 = Vf - fV;
        // fU*32+fV exact small ints; rel in [0, 1024)
        const int rel = (int)fmaf(fU, (float)TSW, fV);
        const __half2 x00 = *(const __half2*)(tl + rel);
        const __half2 x01 = *(const __half2*)(tl + rel + 1);
        const __half2 x10 = *(const __half2*)(tl + rel + TSW);
        const __half2 x11 = *(const __half2*)(tl + rel + TSW + 1);
        const __half2 wv2 = __float2half2_rn(wV1);
        const __half2 wu2 = __float2half2_rn(wU1);
        const __half2 t0 = __hfma2(wv2, __hsub2(x01, x00), x00);
        const __half2 t1 = __hfma2(wv2, __hsub2(x11, x10), x10);
        __half2 v = __hfma2(wu2, __hsub2(t1, t0), t0);
        if (TAIL && k >= iexc) v = __float2half2_rn(0.0f);   // phantom i >= G
        acc = __hadd2(acc, v);
    }
    a0 += __low2float(acc);
    a1 += __high2float(acc);
}

// ------ main gather: wave-private 2-deep double-buffer, counted vmcnt ------
__global__ __launch_bounds__(256) void radon_wv6(
    const unsigned* __restrict__ xIh, const unsigned* __restrict__ xTIh,
    const int* __restrict__ theta, const int4* __restrict__ bbox4,
    float* __restrict__ out)
{
    __shared__ unsigned tile[4 * 2 * TSW * TSW];   // 32,768 B -> 5 blocks/CU

    const int blk  = blockIdx.x;           // 0..2159
    const int t    = blk / NJB;
    const int jb   = blk - t * NJB;
    const int tid  = threadIdx.x;
    const int lane = tid & 63;
    const int wid  = tid >> 6;             // 0..3
    const int wj   = wid & 1;              // j half (16)
    const int wi   = wid >> 1;             // i half (192)
    const int jl   = lane & 15;            // j lane
    const int kk   = lane >> 4;            // i 6-group (0..3)

    unsigned* tileW = tile + wid * (2 * TSW * TSW);   // this wave's 2 bufs

    // ---- prefetch this wave's 8 bbox origins (4 static int4 loads) ----
    const int ws = ((t * NJB + jb) * 2 + wj) * 2 + wi;   // wave slot
    const int4 bb0 = bbox4[ws * 4 + 0];    // {r0[0],c0[0],r0[1],c0[1]}
    const int4 bb1 = bbox4[ws * 4 + 1];
    const int4 bb2 = bbox4[ws * 4 + 2];
    const int4 bb3 = bbox4[ws * 4 + 3];

    const float th = (float)theta[t] * DEG2RAD;
    const float c = cosf(th), s = sinf(th);
    const float s181 = s * 181.0f, c181 = c * 181.0f;

    const int caseA = (fabsf(c) >= fabsf(s));
    const unsigned* __restrict__ srcC = caseA ? xIh : xTIh;

    const float slopeU = caseA ? c181 : s181;
    const float slopeV = caseA ? s181 : c181;
    const float dU = slopeU * STEP;
    const float dV = slopeV * STEP;

    // per-lane sample base (U(i) = dU*i + U00L, padded-grid coords)
    const int   j  = jb * 32 + wj * 16 + jl;   // phantom j >= 363 ok
    const float xj = fmaf((float)j, STEP, -1.0f);
    const float bx = fmaf(c,  xj, 1.0f) * 181.0f;
    const float by = fmaf(-s, xj, 1.0f) * 181.0f;
    const float U00L = (caseA ? by : bx) - slopeU;
    const float V00L = (caseA ? bx : by) - slopeV;

    const float fiofs = (float)(kk * 6);

    float a0 = 0.f, a1 = 0.f;

    // static origin select for subtile u
    auto origin = [&](int u, int& r, int& cc) {
        if      (u == 0) { r = bb0.x; cc = bb0.y; }
        else if (u == 1) { r = bb0.z; cc = bb0.w; }
        else if (u == 2) { r = bb1.x; cc = bb1.y; }
        else if (u == 3) { r = bb1.z; cc = bb1.w; }
        else if (u == 4) { r = bb2.x; cc = bb2.y; }
        else if (u == 5) { r = bb2.z; cc = bb2.w; }
        else if (u == 6) { r = bb3.x; cc = bb3.y; }
        else             { r = bb3.z; cc = bb3.w; }
    };
    auto dostage = [&](int bufsel, int r0, int c0) {
        char* b = (char*)(tileW + bufsel * (TSW * TSW));
        const int r0p = r0 - PADB, c0p = c0 - PADB;
        if (r0p >= -4 && r0p <= 228 && c0p >= -4 && c0p <= 228)
            stage32<true >(b, srcC, r0p, c0p, lane);
        else
            stage32<false>(b, srcC, r0p, c0p, lane);
    };

    // ---- prologue: stage subtile 0 into buf 0 ----
    int r0i, c0i;
    origin(0, r0i, c0i);
    int r0c = __builtin_amdgcn_readfirstlane(r0i);
    int c0c = __builtin_amdgcn_readfirstlane(c0i);
    dostage(0, r0c, c0c);

    #pragma unroll
    for (int sub = 0; sub < 8; ++sub) {
        int r0n = 0, c0n = 0;
        if (sub < 7) {
            origin(sub + 1, r0i, c0i);
            r0n = __builtin_amdgcn_readfirstlane(r0i);
            c0n = __builtin_amdgcn_readfirstlane(c0i);
            // buf being overwritten was last read by gather(sub-1): drained
            asm volatile("s_waitcnt lgkmcnt(0)" ::: "memory");
            __builtin_amdgcn_sched_barrier(0);
            dostage((sub + 1) & 1, r0n, c0n);
            // counted: next's 4 loads stay in flight; current buf complete
            asm volatile("s_waitcnt vmcnt(4)" ::: "memory");
        } else {
            asm volatile("s_waitcnt vmcnt(0)" ::: "memory");
        }
        __builtin_amdgcn_sched_barrier(0);

        // ---- gather 6 taps/lane from current buffer ----
        const unsigned* buf = tileW + (sub & 1) * (TSW * TSW);
        const int i0 = (wi * 8 + sub) * 24;
        const float fi  = (float)i0 + fiofs;
        const float Uf0 = fmaf(dU, fi, U00L) - (float)r0c;
        const float Vf0 = fmaf(dV, fi, V00L) - (float)c0c;
        const int ibase = i0 + kk * 6;

        if (i0 + 23 < G) {
            gather6<false>(buf, Uf0, Vf0, dU, dV, 6, a0, a1);
        } else {
            gather6<true>(buf, Uf0, Vf0, dU, dV, G - ibase, a0, a1);
        }

        r0c = r0n; c0c = c0n;
    }

    // ---- reduce kk groups in-wave, wi halves across waves ----
    // red storage reuses this wave's buf0 (dead; same-wave DS order safe)
    a0 += __shfl_xor(a0, 16); a1 += __shfl_xor(a1, 16);
    a0 += __shfl_xor(a0, 32); a1 += __shfl_xor(a1, 32);

    float* redw = (float*)tileW;
    if (lane < 16) {
        redw[lane]      = a0;
        redw[16 + lane] = a1;
    }
    __syncthreads();

    if (tid < 64) {
        const int n = tid >> 5, jj = tid & 31;
        const int wj2 = jj >> 4, jl2 = jj & 15;
        const float* rA = (const float*)(tile + wj2       * (2 * TSW * TSW));
        const float* rB = (const float*)(tile + (wj2 + 2) * (2 * TSW * TSW));
        const float v = rA[n * 16 + jl2] + rB[n * 16 + jl2];
        const int jo = jb * 32 + jj;
        if (jo < G)
            out[(n * G + jo) * NT + t] = v;
    }
}

extern "C" void kernel_launch(void* const* d_in, const int* in_sizes, int n_in,
                              void* d_out, int out_size, void* d_ws, size_t ws_size,
                              hipStream_t stream) {
    const float* x     = (const float*)d_in[0];
    const int*   theta = (const int*)d_in[1];
    float*       out   = (float*)d_out;

    const size_t XIH_OFF  = 0;
    const size_t XTIH_OFF = (size_t)CH * CW * 4;                 // 278,784
    const size_t BBOX_OFF = 2 * XTIH_OFF;                        // 557,568
    const size_t NEED     = BBOX_OFF + (size_t)NTUPLE * 8;       // ~1.08 MB

    if (ws_size < NEED) {   // fallback: known-good gather kernel
        hipLaunchKernelGGL(radon_fwd, dim3(NT * NJBF), dim3(64, 4), 0, stream,
                           x, theta, out);
        return;
    }

    unsigned* xIh  = (unsigned*)((char*)d_ws + XIH_OFF);
    unsigned* xTIh = (unsigned*)((char*)d_ws + XTIH_OFF);
    int2*     bbox = (int2*)((char*)d_ws + BBOX_OFF);

    hipLaunchKernelGGL(prep_k, dim3(351), dim3(32, 8), 0, stream,
                       x, theta, xIh, xTIh, bbox);
    hipLaunchKernelGGL(radon_wv6, dim3(NT * NJB), dim3(256), 0, stream,
                       xIh, xTIh, theta, (const int4*)bbox, out);
}

// Round 17
// 32.469 us; speedup vs baseline: 1.0225x; 1.0225x over previous
//
#include <hip/hip_runtime.h>
#include <hip/hip_fp16.h>
#include <math.h>

// Radon forward, exact reference semantics (rotated-lattice bilinear gather).
//
// Round-23: identical to round-22 (phase-split gather) with the compile fix:
//  * __half2_as_uint / __uint_as_half2 do not exist in HIP -- the phase-A
//    precomputed weights are stored directly as __half2 arrays (same
//    registers, no bit-cast).
//  * Recap of r22 change vs champion r20 (32.05 us): per subtile, the 6
//    taps' address/weight VALU (~96 cyc, independent of staged data) is
//    computed BETWEEN stage-issue and the wave-local vmcnt(0) drain --
//    hiding inside the ~400 cyc L2 latency instead of after it. Phase B
//    (LDS loads + packed-f16 lerp) runs after the drain.
//  * Everything else byte-identical to r20 (bbox table, wave-private
//    single-buffer tiles, barrier-free main loop).

#define G       363
#define NT      180
#define PADB    53
#define STEP    (2.0f / 362.0f)
#define DEG2RAD 0.017453292519943295f

#define TSW     32          // tile row length (u32 cells)
#define NJB     12          // j-blocks of 32
#define NJBF    6           // fallback j-blocks of 64
#define CW      264         // canvas cols (4 guard + 256 + 4 guard)
#define CH      264         // canvas rows
#define NWSLOT  (NT * NJB * 2 * 2)     // 8640 wave slots
#define NTUPLE  (NWSLOT * 8)           // 69120 subtile origins

#define GLOAD16(gp, lp) __builtin_amdgcn_global_load_lds(                     \
    (const __attribute__((address_space(1))) void*)(gp),                      \
    (__attribute__((address_space(3))) void*)(lp), 16, 0, 0)

// ---------------- fallback gather kernel (known-good, round 1) -------------
__global__ __launch_bounds__(256) void radon_fwd(
    const float* __restrict__ x, const int* __restrict__ theta,
    float* __restrict__ out)
{
    const int t = blockIdx.x / NJBF, jb = blockIdx.x % NJBF;
    const int jl = threadIdx.x, chunk = threadIdx.y;
    const int j = jb * 64 + jl;
    const float th = (float)theta[t] * DEG2RAD;
    const float c = cosf(th), s = sinf(th);
    const float xj = fmaf((float)j, STEP, -1.0f);
    const float s181 = s * 181.0f, c181 = c * 181.0f;
    const float bx = fmaf(c, xj, 1.0f) * 181.0f;
    const float by = fmaf(-s, xj, 1.0f) * 181.0f;
    const float* img0 = x;
    const float* img1 = x + 65536;
    float acc0 = 0.f, acc1 = 0.f;
    for (int i = chunk; i < G; i += 4) {
        const float xi = fmaf((float)i, STEP, -1.0f);
        const float ix = fmaf(s181, xi, bx);
        const float iy = fmaf(c181, xi, by);
        const float fx = floorf(ix), fy = floorf(iy);
        const int ix0 = (int)fx, iy0 = (int)fy;
        const float wx1 = ix - fx, wy1 = iy - fy;
        const float wx0 = 1.f - wx1, wy0 = 1.f - wy1;
        const int cc0 = ix0 - 53, cc1 = cc0 + 1, rr0 = iy0 - 53, rr1 = rr0 + 1;
        const float wxa = ((unsigned)cc0 < 256u) ? wx0 : 0.f;
        const float wxb = ((unsigned)cc1 < 256u) ? wx1 : 0.f;
        const float wya = ((unsigned)rr0 < 256u) ? wy0 : 0.f;
        const float wyb = ((unsigned)rr1 < 256u) ? wy1 : 0.f;
        const int c0c = min(max(cc0, 0), 255), c1c = min(max(cc1, 0), 255);
        const int r0b = min(max(rr0, 0), 255) << 8, r1b = min(max(rr1, 0), 255) << 8;
        const float w00 = wya * wxa, w01 = wya * wxb, w10 = wyb * wxa, w11 = wyb * wxb;
        acc0 = fmaf(img0[r0b + c0c], w00, acc0);
        acc0 = fmaf(img0[r0b + c1c], w01, acc0);
        acc0 = fmaf(img0[r1b + c0c], w10, acc0);
        acc0 = fmaf(img0[r1b + c1c], w11, acc0);
        acc1 = fmaf(img1[r0b + c0c], w00, acc1);
        acc1 = fmaf(img1[r0b + c1c], w01, acc1);
        acc1 = fmaf(img1[r1b + c0c], w10, acc1);
        acc1 = fmaf(img1[r1b + c1c], w11, acc1);
    }
    __shared__ float red[2][4][64];
    red[0][chunk][jl] = acc0;
    red[1][chunk][jl] = acc1;
    __syncthreads();
    if (threadIdx.y < 2 && j < G) {
        const int n = threadIdx.y;
        out[n * (G * NT) + j * NT + t] =
            red[n][0][jl] + red[n][1][jl] + red[n][2][jl] + red[n][3][jl];
    }
}

// --------- prep: f16x2 canvases + per-(wave,sub) bbox-origin table ---------
// Blocks [0,81): canvases.  [81,351): bbox table (one tuple per thread).
__global__ __launch_bounds__(256) void prep_k(
    const float* __restrict__ x, const int* __restrict__ theta,
    unsigned* __restrict__ xIh, unsigned* __restrict__ xTIh,
    int2* __restrict__ bbox)
{
    const int bid = blockIdx.x;
    const int tx = threadIdx.x, ty = threadIdx.y;
    const int tid = ty * 32 + tx;

    if (bid < 81) {
        __shared__ unsigned tl[32][33];
        const int cx0 = (bid % 9) * 32, cy0 = (bid / 9) * 32;
        #pragma unroll
        for (int dy = 0; dy < 32; dy += 8) {
            const int cy = cy0 + ty + dy, cx = cx0 + tx;
            const int pr = cy - 4, pc = cx - 4;
            unsigned v = 0u;
            if ((unsigned)pr < 256u && (unsigned)pc < 256u) {
                const int p = pr * 256 + pc;
                const unsigned short a = __half_as_ushort(__float2half_rn(x[p]));
                const unsigned short b = __half_as_ushort(__float2half_rn(x[p + 65536]));
                v = (unsigned)a | ((unsigned)b << 16);
            }
            if (cy < CH && cx < CW) xIh[cy * CW + cx] = v;
            tl[ty + dy][tx] = v;
        }
        __syncthreads();
        #pragma unroll
        for (int dy = 0; dy < 32; dy += 8) {
            const int rp = cx0 + ty + dy, cp = cy0 + tx;
            if (rp < CH && cp < CW) xTIh[rp * CW + cp] = tl[tx][ty + dy];
        }
    } else {
        const int tuple = (bid - 81) * 256 + tid;
        if (tuple < NTUPLE) {
            // decode: (((t*NJB + jb)*2 + wj)*2 + wi)*8 + sub
            const int sub = tuple & 7;
            const int ws  = tuple >> 3;
            const int wi  = ws & 1;
            const int wj  = (ws >> 1) & 1;
            const int jb  = (ws >> 2) % NJB;
            const int t   = (ws >> 2) / NJB;

            // ---- identical fmaf chain to the main kernel ----
            const float th = (float)theta[t] * DEG2RAD;
            const float c = cosf(th), s = sinf(th);
            const float s181 = s * 181.0f, c181 = c * 181.0f;
            const int caseA = (fabsf(c) >= fabsf(s));
            const float slopeU = caseA ? c181 : s181;
            const float slopeV = caseA ? s181 : c181;
            const float dU = slopeU * STEP;
            const float dV = slopeV * STEP;

            const int   j0  = jb * 32 + wj * 16;
            const float xjm = fmaf((float)j0,        STEP, -1.0f);
            const float xjM = fmaf((float)(j0 + 15), STEP, -1.0f);
            const float bxm = fmaf(c,  xjm, 1.0f) * 181.0f;
            const float bym = fmaf(-s, xjm, 1.0f) * 181.0f;
            const float bxM = fmaf(c,  xjM, 1.0f) * 181.0f;
            const float byM = fmaf(-s, xjM, 1.0f) * 181.0f;
            const float U00m = (caseA ? bym : bxm) - slopeU;
            const float U00M = (caseA ? byM : bxM) - slopeU;
            const float V00m = (caseA ? bxm : bym) - slopeV;
            const float V00M = (caseA ? bxM : byM) - slopeV;

            const int i0 = (wi * 8 + sub) * 24;
            const float fi0 = (float)i0, fi1 = (float)(i0 + 23);
            const float Umin = fminf(fminf(fmaf(dU, fi0, U00m), fmaf(dU, fi0, U00M)),
                                     fminf(fmaf(dU, fi1, U00m), fmaf(dU, fi1, U00M)));
            const float Vmin = fminf(fminf(fmaf(dV, fi0, V00m), fmaf(dV, fi0, V00M)),
                                     fminf(fmaf(dV, fi1, V00m), fmaf(dV, fi1, V00M)));
            const int r0 = (int)floorf(Umin) - 1;
            const int c0 = (int)floorf(Vmin) - 1;
            bbox[tuple] = make_int2(r0, c0);
        }
    }
}

// ---------------- staging: 4x global_load_lds into wave-private 32x32 ------
template<bool SAFE>
__device__ __forceinline__ void stage32(char* tileW_b,
    const unsigned* __restrict__ srcC, int r0p, int c0p, int lane)
{
    const int ty0 = lane >> 3;             // 0..7
    const int tx  = (lane & 7) << 2;       // 0,4,...,28 (4 cells/lane)
    #pragma unroll
    for (int u = 0; u < 4; ++u) {
        const int ty = ty0 + (u << 3);
        int idx;
        if (SAFE) {
            idx = (r0p + 4 + ty) * CW + (c0p + 4 + tx);
        } else {
            // clamp into 4-wide zero guard: OOB taps read guaranteed zeros
            const int rc = min(max(r0p + ty, -4), 256) + 4;
            const int cc = min(max(c0p + tx, -4), 256) + 4;
            idx = rc * CW + cc;
        }
        GLOAD16(srcC + idx, tileW_b + (u << 10));
    }
}

// -------- gather, phase A: per-tap addresses + weights (no LDS access) -----
__device__ __forceinline__ void gather6_pre(
    float Uf0, float Vf0, float dU, float dV,
    int (&rel)[6], __half2 (&wu)[6], __half2 (&wv)[6])
{
    #pragma unroll
    for (int k = 0; k < 6; ++k) {
        const float Uf = fmaf((float)k, dU, Uf0);   // independent, no chain
        const float Vf = fmaf((float)k, dV, Vf0);
        const float fU = floorf(Uf), fV = floorf(Vf);
        const float wU1 = Uf - fU;
        const float wV1 = Vf - fV;
        // fU*32+fV exact small ints; rel in [0, 1024)
        rel[k] = (int)fmaf(fU, (float)TSW, fV);
        wu[k] = __float2half2_rn(wU1);
        wv[k] = __float2half2_rn(wV1);
    }
}

// -------- gather, phase B: LDS loads + packed-f16 lerp (after drain) -------
template<bool TAIL>
__device__ __forceinline__ void gather6_post(const unsigned* __restrict__ tl,
    const int (&rel)[6], const __half2 (&wu)[6], const __half2 (&wv)[6],
    int iexc, float& a0, float& a1)
{
    __half2 acc = __float2half2_rn(0.0f);
    #pragma unroll
    for (int k = 0; k < 6; ++k) {
        const int r = rel[k];
        const __half2 x00 = *(const __half2*)(tl + r);
        const __half2 x01 = *(const __half2*)(tl + r + 1);
        const __half2 x10 = *(const __half2*)(tl + r + TSW);
        const __half2 x11 = *(const __half2*)(tl + r + TSW + 1);
        const __half2 wv2 = wv[k];
        const __half2 wu2 = wu[k];
        const __half2 t0 = __hfma2(wv2, __hsub2(x01, x00), x00);
        const __half2 t1 = __hfma2(wv2, __hsub2(x11, x10), x10);
        __half2 v = __hfma2(wu2, __hsub2(t1, t0), t0);
        if (TAIL && k >= iexc) v = __float2half2_rn(0.0f);   // phantom i >= G
        acc = __hadd2(acc, v);
    }
    a0 += __low2float(acc);
    a1 += __high2float(acc);
}

// ---------------- main gather: barrier-free wave-private tiles -------------
__global__ __launch_bounds__(256) void radon_wv7(
    const unsigned* __restrict__ xIh, const unsigned* __restrict__ xTIh,
    const int* __restrict__ theta, const int4* __restrict__ bbox4,
    float* __restrict__ out)
{
    __shared__ unsigned tile[4 * TSW * TSW];   // 4 waves x 4 KB, private
    __shared__ float red[4][2][16];

    const int blk  = blockIdx.x;           // 0..2159
    const int t    = blk / NJB;
    const int jb   = blk - t * NJB;
    const int tid  = threadIdx.x;
    const int lane = tid & 63;
    const int wid  = tid >> 6;             // 0..3
    const int wj   = wid & 1;              // j half (16)
    const int wi   = wid >> 1;             // i half (192)
    const int jl   = lane & 15;            // j lane
    const int kk   = lane >> 4;            // i 6-group (0..3)

    unsigned* tileW = tile + wid * (TSW * TSW);
    char*     tileW_b = (char*)tileW;

    // ---- prefetch this wave's 8 bbox origins (4 static int4 loads) ----
    const int ws = ((t * NJB + jb) * 2 + wj) * 2 + wi;   // wave slot
    const int4 bb0 = bbox4[ws * 4 + 0];    // {r0[0],c0[0],r0[1],c0[1]}
    const int4 bb1 = bbox4[ws * 4 + 1];
    const int4 bb2 = bbox4[ws * 4 + 2];
    const int4 bb3 = bbox4[ws * 4 + 3];

    const float th = (float)theta[t] * DEG2RAD;
    const float c = cosf(th), s = sinf(th);
    const float s181 = s * 181.0f, c181 = c * 181.0f;

    const int caseA = (fabsf(c) >= fabsf(s));
    const unsigned* __restrict__ srcC = caseA ? xIh : xTIh;

    const float slopeU = caseA ? c181 : s181;
    const float slopeV = caseA ? s181 : c181;
    const float dU = slopeU * STEP;
    const float dV = slopeV * STEP;

    // per-lane sample base (U(i) = dU*i + U00L, padded-grid coords)
    const int   j  = jb * 32 + wj * 16 + jl;   // phantom j >= 363 ok
    const float xj = fmaf((float)j, STEP, -1.0f);
    const float bx = fmaf(c,  xj, 1.0f) * 181.0f;
    const float by = fmaf(-s, xj, 1.0f) * 181.0f;
    const float U00L = (caseA ? by : bx) - slopeU;
    const float V00L = (caseA ? bx : by) - slopeV;

    const float fiofs = (float)(kk * 6);

    float a0 = 0.f, a1 = 0.f;

    #pragma unroll
    for (int sub = 0; sub < 8; ++sub) {
        // ---- static extraction of this subtile's origin ----
        int r0i, c0i;
        if      (sub == 0) { r0i = bb0.x; c0i = bb0.y; }
        else if (sub == 1) { r0i = bb0.z; c0i = bb0.w; }
        else if (sub == 2) { r0i = bb1.x; c0i = bb1.y; }
        else if (sub == 3) { r0i = bb1.z; c0i = bb1.w; }
        else if (sub == 4) { r0i = bb2.x; c0i = bb2.y; }
        else if (sub == 5) { r0i = bb2.z; c0i = bb2.w; }
        else if (sub == 6) { r0i = bb3.x; c0i = bb3.y; }
        else               { r0i = bb3.z; c0i = bb3.w; }
        const int r0 = __builtin_amdgcn_readfirstlane(r0i);
        const int c0 = __builtin_amdgcn_readfirstlane(c0i);
        const int r0p = r0 - PADB, c0p = c0 - PADB;

        // ---- fence: prior subtile's ds_reads done before overwrite ----
        asm volatile("s_waitcnt lgkmcnt(0)" ::: "memory");
        __builtin_amdgcn_sched_barrier(0);

        if (r0p >= -4 && r0p <= 228 && c0p >= -4 && c0p <= 228)
            stage32<true >(tileW_b, srcC, r0p, c0p, lane);
        else
            stage32<false>(tileW_b, srcC, r0p, c0p, lane);

        // ---- phase A: tap addresses/weights, hidden under the drain ----
        const int i0 = (wi * 8 + sub) * 24;
        const float fi  = (float)i0 + fiofs;
        const float Uf0 = fmaf(dU, fi, U00L) - (float)r0;
        const float Vf0 = fmaf(dV, fi, V00L) - (float)c0;
        const int ibase = i0 + kk * 6;

        int rel[6]; __half2 wu[6], wv[6];
        gather6_pre(Uf0, Vf0, dU, dV, rel, wu, wv);

        // ---- wave-local drain; NO block barrier ----
        asm volatile("s_waitcnt vmcnt(0)" ::: "memory");
        __builtin_amdgcn_sched_barrier(0);

        // ---- phase B: gather 6 taps/lane from the staged tile ----
        if (i0 + 23 < G) {
            gather6_post<false>(tileW, rel, wu, wv, 6, a0, a1);
        } else {
            gather6_post<true>(tileW, rel, wu, wv, G - ibase, a0, a1);
        }
    }

    // ---- reduce kk groups in-wave, wi halves across waves ----
    a0 += __shfl_xor(a0, 16); a1 += __shfl_xor(a1, 16);
    a0 += __shfl_xor(a0, 32); a1 += __shfl_xor(a1, 32);

    if (lane < 16) {
        red[wid][0][lane] = a0;
        red[wid][1][lane] = a1;
    }
    __syncthreads();

    if (tid < 64) {
        const int n = tid >> 5, jj = tid & 31;
        const int wj2 = jj >> 4, jl2 = jj & 15;
        const float v = red[wj2][n][jl2] + red[wj2 + 2][n][jl2];
        const int jo = jb * 32 + jj;
        if (jo < G)
            out[(n * G + jo) * NT + t] = v;
    }
}

extern "C" void kernel_launch(void* const* d_in, const int* in_sizes, int n_in,
                              void* d_out, int out_size, void* d_ws, size_t ws_size,
                              hipStream_t stream) {
    const float* x     = (const float*)d_in[0];
    const int*   theta = (const int*)d_in[1];
    float*       out   = (float*)d_out;

    const size_t XIH_OFF  = 0;
    const size_t XTIH_OFF = (size_t)CH * CW * 4;                 // 278,784
    const size_t BBOX_OFF = 2 * XTIH_OFF;                        // 557,568
    const size_t NEED     = BBOX_OFF + (size_t)NTUPLE * 8;       // ~1.08 MB

    if (ws_size < NEED) {   // fallback: known-good gather kernel
        hipLaunchKernelGGL(radon_fwd, dim3(NT * NJBF), dim3(64, 4), 0, stream,
                           x, theta, out);
        return;
    }

    unsigned* xIh  = (unsigned*)((char*)d_ws + XIH_OFF);
    unsigned* xTIh = (unsigned*)((char*)d_ws + XTIH_OFF);
    int2*     bbox = (int2*)((char*)d_ws + BBOX_OFF);

    hipLaunchKernelGGL(prep_k, dim3(351), dim3(32, 8), 0, stream,
                       x, theta, xIh, xTIh, bbox);
    hipLaunchKernelGGL(radon_wv7, dim3(NT * NJB), dim3(256), 0, stream,
                       xIh, xTIh, theta, (const int4*)bbox, out);
}

// Round 18
// 32.034 us; speedup vs baseline: 1.0364x; 1.0136x over previous
//
#include <hip/hip_runtime.h>
#include <hip/hip_fp16.h>
#include <math.h>

// Radon forward, exact reference semantics (rotated-lattice bilinear gather).
//
// FINAL (round-24): revert to round-20 champion (32.05 us), the measured
// plateau of this structure family. Session: 68.9 -> 32.05 us (2.15x).
//
// Structure (validated over rounds 12-23):
//  * f16x2-packed canvases {img0,img1} (u32 cells), normal + transposed,
//    4-wide zero guard ring -- both L2-resident (558 KB).
//  * Barrier-free wave-private 32x32-cell LDS tiles (4 KB/wave): each wave
//    stages its own subtile via 4x global_load_lds and syncs with
//    wave-local s_waitcnt only (no __syncthreads in the main loop).
//  * Per-(wave,subtile) bbox origins precomputed in prep (identical fmaf
//    chain -> bit-identical, +-1 margin proof preserved); main kernel
//    loads its 8 origins as 4 static int4 loads (in-loop cost: 2
//    readfirstlanes).
//  * Packed-f16 two-lerp interpolation (both images per v_pk_fma_f16),
//    f16 accumulate per 6 taps, f32 across subtiles.
//  * Refuted levers (counters, rounds 15-23): L2-direct gather (+6),
//    depth-2 dbuf (+1.1), stride-36 banks (+2.6), rotation swizzle (+11),
//    phase-split (+0.4), block-level pipelining (+2..8).

#define G       363
#define NT      180
#define PADB    53
#define STEP    (2.0f / 362.0f)
#define DEG2RAD 0.017453292519943295f

#define TSW     32          // tile row length (u32 cells)
#define NJB     12          // j-blocks of 32
#define NJBF    6           // fallback j-blocks of 64
#define CW      264         // canvas cols (4 guard + 256 + 4 guard)
#define CH      264         // canvas rows
#define NWSLOT  (NT * NJB * 2 * 2)     // 8640 wave slots
#define NTUPLE  (NWSLOT * 8)           // 69120 subtile origins

#define GLOAD16(gp, lp) __builtin_amdgcn_global_load_lds(                     \
    (const __attribute__((address_space(1))) void*)(gp),                      \
    (__attribute__((address_space(3))) void*)(lp), 16, 0, 0)

// ---------------- fallback gather kernel (known-good, round 1) -------------
__global__ __launch_bounds__(256) void radon_fwd(
    const float* __restrict__ x, const int* __restrict__ theta,
    float* __restrict__ out)
{
    const int t = blockIdx.x / NJBF, jb = blockIdx.x % NJBF;
    const int jl = threadIdx.x, chunk = threadIdx.y;
    const int j = jb * 64 + jl;
    const float th = (float)theta[t] * DEG2RAD;
    const float c = cosf(th), s = sinf(th);
    const float xj = fmaf((float)j, STEP, -1.0f);
    const float s181 = s * 181.0f, c181 = c * 181.0f;
    const float bx = fmaf(c, xj, 1.0f) * 181.0f;
    const float by = fmaf(-s, xj, 1.0f) * 181.0f;
    const float* img0 = x;
    const float* img1 = x + 65536;
    float acc0 = 0.f, acc1 = 0.f;
    for (int i = chunk; i < G; i += 4) {
        const float xi = fmaf((float)i, STEP, -1.0f);
        const float ix = fmaf(s181, xi, bx);
        const float iy = fmaf(c181, xi, by);
        const float fx = floorf(ix), fy = floorf(iy);
        const int ix0 = (int)fx, iy0 = (int)fy;
        const float wx1 = ix - fx, wy1 = iy - fy;
        const float wx0 = 1.f - wx1, wy0 = 1.f - wy1;
        const int cc0 = ix0 - 53, cc1 = cc0 + 1, rr0 = iy0 - 53, rr1 = rr0 + 1;
        const float wxa = ((unsigned)cc0 < 256u) ? wx0 : 0.f;
        const float wxb = ((unsigned)cc1 < 256u) ? wx1 : 0.f;
        const float wya = ((unsigned)rr0 < 256u) ? wy0 : 0.f;
        const float wyb = ((unsigned)rr1 < 256u) ? wy1 : 0.f;
        const int c0c = min(max(cc0, 0), 255), c1c = min(max(cc1, 0), 255);
        const int r0b = min(max(rr0, 0), 255) << 8, r1b = min(max(rr1, 0), 255) << 8;
        const float w00 = wya * wxa, w01 = wya * wxb, w10 = wyb * wxa, w11 = wyb * wxb;
        acc0 = fmaf(img0[r0b + c0c], w00, acc0);
        acc0 = fmaf(img0[r0b + c1c], w01, acc0);
        acc0 = fmaf(img0[r1b + c0c], w10, acc0);
        acc0 = fmaf(img0[r1b + c1c], w11, acc0);
        acc1 = fmaf(img1[r0b + c0c], w00, acc1);
        acc1 = fmaf(img1[r0b + c1c], w01, acc1);
        acc1 = fmaf(img1[r1b + c0c], w10, acc1);
        acc1 = fmaf(img1[r1b + c1c], w11, acc1);
    }
    __shared__ float red[2][4][64];
    red[0][chunk][jl] = acc0;
    red[1][chunk][jl] = acc1;
    __syncthreads();
    if (threadIdx.y < 2 && j < G) {
        const int n = threadIdx.y;
        out[n * (G * NT) + j * NT + t] =
            red[n][0][jl] + red[n][1][jl] + red[n][2][jl] + red[n][3][jl];
    }
}

// --------- prep: f16x2 canvases + per-(wave,sub) bbox-origin table ---------
// Blocks [0,81): canvases.  [81,351): bbox table (one tuple per thread).
__global__ __launch_bounds__(256) void prep_k(
    const float* __restrict__ x, const int* __restrict__ theta,
    unsigned* __restrict__ xIh, unsigned* __restrict__ xTIh,
    int2* __restrict__ bbox)
{
    const int bid = blockIdx.x;
    const int tx = threadIdx.x, ty = threadIdx.y;
    const int tid = ty * 32 + tx;

    if (bid < 81) {
        __shared__ unsigned tl[32][33];
        const int cx0 = (bid % 9) * 32, cy0 = (bid / 9) * 32;
        #pragma unroll
        for (int dy = 0; dy < 32; dy += 8) {
            const int cy = cy0 + ty + dy, cx = cx0 + tx;
            const int pr = cy - 4, pc = cx - 4;
            unsigned v = 0u;
            if ((unsigned)pr < 256u && (unsigned)pc < 256u) {
                const int p = pr * 256 + pc;
                const unsigned short a = __half_as_ushort(__float2half_rn(x[p]));
                const unsigned short b = __half_as_ushort(__float2half_rn(x[p + 65536]));
                v = (unsigned)a | ((unsigned)b << 16);
            }
            if (cy < CH && cx < CW) xIh[cy * CW + cx] = v;
            tl[ty + dy][tx] = v;
        }
        __syncthreads();
        #pragma unroll
        for (int dy = 0; dy < 32; dy += 8) {
            const int rp = cx0 + ty + dy, cp = cy0 + tx;
            if (rp < CH && cp < CW) xTIh[rp * CW + cp] = tl[tx][ty + dy];
        }
    } else {
        const int tuple = (bid - 81) * 256 + tid;
        if (tuple < NTUPLE) {
            // decode: (((t*NJB + jb)*2 + wj)*2 + wi)*8 + sub
            const int sub = tuple & 7;
            const int ws  = tuple >> 3;
            const int wi  = ws & 1;
            const int wj  = (ws >> 1) & 1;
            const int jb  = (ws >> 2) % NJB;
            const int t   = (ws >> 2) / NJB;

            // ---- identical fmaf chain to the main kernel ----
            const float th = (float)theta[t] * DEG2RAD;
            const float c = cosf(th), s = sinf(th);
            const float s181 = s * 181.0f, c181 = c * 181.0f;
            const int caseA = (fabsf(c) >= fabsf(s));
            const float slopeU = caseA ? c181 : s181;
            const float slopeV = caseA ? s181 : c181;
            const float dU = slopeU * STEP;
            const float dV = slopeV * STEP;

            const int   j0  = jb * 32 + wj * 16;
            const float xjm = fmaf((float)j0,        STEP, -1.0f);
            const float xjM = fmaf((float)(j0 + 15), STEP, -1.0f);
            const float bxm = fmaf(c,  xjm, 1.0f) * 181.0f;
            const float bym = fmaf(-s, xjm, 1.0f) * 181.0f;
            const float bxM = fmaf(c,  xjM, 1.0f) * 181.0f;
            const float byM = fmaf(-s, xjM, 1.0f) * 181.0f;
            const float U00m = (caseA ? bym : bxm) - slopeU;
            const float U00M = (caseA ? byM : bxM) - slopeU;
            const float V00m = (caseA ? bxm : bym) - slopeV;
            const float V00M = (caseA ? bxM : byM) - slopeV;

            const int i0 = (wi * 8 + sub) * 24;
            const float fi0 = (float)i0, fi1 = (float)(i0 + 23);
            const float Umin = fminf(fminf(fmaf(dU, fi0, U00m), fmaf(dU, fi0, U00M)),
                                     fminf(fmaf(dU, fi1, U00m), fmaf(dU, fi1, U00M)));
            const float Vmin = fminf(fminf(fmaf(dV, fi0, V00m), fmaf(dV, fi0, V00M)),
                                     fminf(fmaf(dV, fi1, V00m), fmaf(dV, fi1, V00M)));
            const int r0 = (int)floorf(Umin) - 1;
            const int c0 = (int)floorf(Vmin) - 1;
            bbox[tuple] = make_int2(r0, c0);
        }
    }
}

// ---------------- staging: 4x global_load_lds into wave-private 32x32 ------
template<bool SAFE>
__device__ __forceinline__ void stage32(char* tileW_b,
    const unsigned* __restrict__ srcC, int r0p, int c0p, int lane)
{
    const int ty0 = lane >> 3;             // 0..7
    const int tx  = (lane & 7) << 2;       // 0,4,...,28 (4 cells/lane)
    #pragma unroll
    for (int u = 0; u < 4; ++u) {
        const int ty = ty0 + (u << 3);
        int idx;
        if (SAFE) {
            idx = (r0p + 4 + ty) * CW + (c0p + 4 + tx);
        } else {
            // clamp into 4-wide zero guard: OOB taps read guaranteed zeros
            const int rc = min(max(r0p + ty, -4), 256) + 4;
            const int cc = min(max(c0p + tx, -4), 256) + 4;
            idx = rc * CW + cc;
        }
        GLOAD16(srcC + idx, tileW_b + (u << 10));
    }
}

// ---------------- gather inner loop (6 i-steps, packed-f16 lerp) -----------
template<bool TAIL>
__device__ __forceinline__ void gather6(const unsigned* __restrict__ tl,
    float Uf0, float Vf0, float dU, float dV, int iexc,
    float& a0, float& a1)
{
    __half2 acc = __float2half2_rn(0.0f);
    #pragma unroll
    for (int k = 0; k < 6; ++k) {
        const float Uf = fmaf((float)k, dU, Uf0);   // independent, no chain
        const float Vf = fmaf((float)k, dV, Vf0);
        const float fU = floorf(Uf), fV = floorf(Vf);
        const float wU1 = Uf - fU;
        const float wV1 = Vf - fV;
        // fU*32+fV exact small ints; rel in [0, 1024)
        const int rel = (int)fmaf(fU, (float)TSW, fV);
        const __half2 x00 = *(const __half2*)(tl + rel);
        const __half2 x01 = *(const __half2*)(tl + rel + 1);
        const __half2 x10 = *(const __half2*)(tl + rel + TSW);
        const __half2 x11 = *(const __half2*)(tl + rel + TSW + 1);
        const __half2 wv2 = __float2half2_rn(wV1);
        const __half2 wu2 = __float2half2_rn(wU1);
        const __half2 t0 = __hfma2(wv2, __hsub2(x01, x00), x00);
        const __half2 t1 = __hfma2(wv2, __hsub2(x11, x10), x10);
        __half2 v = __hfma2(wu2, __hsub2(t1, t0), t0);
        if (TAIL && k >= iexc) v = __float2half2_rn(0.0f);   // phantom i >= G
        acc = __hadd2(acc, v);
    }
    a0 += __low2float(acc);
    a1 += __high2float(acc);
}

// ---------------- main gather: barrier-free wave-private tiles -------------
__global__ __launch_bounds__(256) void radon_wv5(
    const unsigned* __restrict__ xIh, const unsigned* __restrict__ xTIh,
    const int* __restrict__ theta, const int4* __restrict__ bbox4,
    float* __restrict__ out)
{
    __shared__ unsigned tile[4 * TSW * TSW];   // 4 waves x 4 KB, private
    __shared__ float red[4][2][16];

    const int blk  = blockIdx.x;           // 0..2159
    const int t    = blk / NJB;
    const int jb   = blk - t * NJB;
    const int tid  = threadIdx.x;
    const int lane = tid & 63;
    const int wid  = tid >> 6;             // 0..3
    const int wj   = wid & 1;              // j half (16)
    const int wi   = wid >> 1;             // i half (192)
    const int jl   = lane & 15;            // j lane
    const int kk   = lane >> 4;            // i 6-group (0..3)

    unsigned* tileW = tile + wid * (TSW * TSW);
    char*     tileW_b = (char*)tileW;

    // ---- prefetch this wave's 8 bbox origins (4 static int4 loads) ----
    const int ws = ((t * NJB + jb) * 2 + wj) * 2 + wi;   // wave slot
    const int4 bb0 = bbox4[ws * 4 + 0];    // {r0[0],c0[0],r0[1],c0[1]}
    const int4 bb1 = bbox4[ws * 4 + 1];
    const int4 bb2 = bbox4[ws * 4 + 2];
    const int4 bb3 = bbox4[ws * 4 + 3];

    const float th = (float)theta[t] * DEG2RAD;
    const float c = cosf(th), s = sinf(th);
    const float s181 = s * 181.0f, c181 = c * 181.0f;

    const int caseA = (fabsf(c) >= fabsf(s));
    const unsigned* __restrict__ srcC = caseA ? xIh : xTIh;

    const float slopeU = caseA ? c181 : s181;
    const float slopeV = caseA ? s181 : c181;
    const float dU = slopeU * STEP;
    const float dV = slopeV * STEP;

    // per-lane sample base (U(i) = dU*i + U00L, padded-grid coords)
    const int   j  = jb * 32 + wj * 16 + jl;   // phantom j >= 363 ok
    const float xj = fmaf((float)j, STEP, -1.0f);
    const float bx = fmaf(c,  xj, 1.0f) * 181.0f;
    const float by = fmaf(-s, xj, 1.0f) * 181.0f;
    const float U00L = (caseA ? by : bx) - slopeU;
    const float V00L = (caseA ? bx : by) - slopeV;

    const float fiofs = (float)(kk * 6);

    float a0 = 0.f, a1 = 0.f;

    #pragma unroll
    for (int sub = 0; sub < 8; ++sub) {
        // ---- static extraction of this subtile's origin ----
        int r0i, c0i;
        if      (sub == 0) { r0i = bb0.x; c0i = bb0.y; }
        else if (sub == 1) { r0i = bb0.z; c0i = bb0.w; }
        else if (sub == 2) { r0i = bb1.x; c0i = bb1.y; }
        else if (sub == 3) { r0i = bb1.z; c0i = bb1.w; }
        else if (sub == 4) { r0i = bb2.x; c0i = bb2.y; }
        else if (sub == 5) { r0i = bb2.z; c0i = bb2.w; }
        else if (sub == 6) { r0i = bb3.x; c0i = bb3.y; }
        else               { r0i = bb3.z; c0i = bb3.w; }
        const int r0 = __builtin_amdgcn_readfirstlane(r0i);
        const int c0 = __builtin_amdgcn_readfirstlane(c0i);
        const int r0p = r0 - PADB, c0p = c0 - PADB;

        // ---- fence: prior subtile's ds_reads done before overwrite ----
        asm volatile("s_waitcnt lgkmcnt(0)" ::: "memory");
        __builtin_amdgcn_sched_barrier(0);

        if (r0p >= -4 && r0p <= 228 && c0p >= -4 && c0p <= 228)
            stage32<true >(tileW_b, srcC, r0p, c0p, lane);
        else
            stage32<false>(tileW_b, srcC, r0p, c0p, lane);

        // ---- wave-local drain; NO block barrier ----
        asm volatile("s_waitcnt vmcnt(0)" ::: "memory");
        __builtin_amdgcn_sched_barrier(0);

        // ---- gather 6 taps/lane, tile-relative coords ----
        const int i0 = (wi * 8 + sub) * 24;
        const float fi  = (float)i0 + fiofs;
        const float Uf0 = fmaf(dU, fi, U00L) - (float)r0;
        const float Vf0 = fmaf(dV, fi, V00L) - (float)c0;
        const int ibase = i0 + kk * 6;

        if (i0 + 23 < G) {
            gather6<false>(tileW, Uf0, Vf0, dU, dV, 6, a0, a1);
        } else {
            gather6<true>(tileW, Uf0, Vf0, dU, dV, G - ibase, a0, a1);
        }
    }

    // ---- reduce kk groups in-wave, wi halves across waves ----
    a0 += __shfl_xor(a0, 16); a1 += __shfl_xor(a1, 16);
    a0 += __shfl_xor(a0, 32); a1 += __shfl_xor(a1, 32);

    if (lane < 16) {
        red[wid][0][lane] = a0;
        red[wid][1][lane] = a1;
    }
    __syncthreads();

    if (tid < 64) {
        const int n = tid >> 5, jj = tid & 31;
        const int wj2 = jj >> 4, jl2 = jj & 15;
        const float v = red[wj2][n][jl2] + red[wj2 + 2][n][jl2];
        const int jo = jb * 32 + jj;
        if (jo < G)
            out[(n * G + jo) * NT + t] = v;
    }
}

extern "C" void kernel_launch(void* const* d_in, const int* in_sizes, int n_in,
                              void* d_out, int out_size, void* d_ws, size_t ws_size,
                              hipStream_t stream) {
    const float* x     = (const float*)d_in[0];
    const int*   theta = (const int*)d_in[1];
    float*       out   = (float*)d_out;

    const size_t XIH_OFF  = 0;
    const size_t XTIH_OFF = (size_t)CH * CW * 4;                 // 278,784
    const size_t BBOX_OFF = 2 * XTIH_OFF;                        // 557,568
    const size_t NEED     = BBOX_OFF + (size_t)NTUPLE * 8;       // ~1.08 MB

    if (ws_size < NEED) {   // fallback: known-good gather kernel
        hipLaunchKernelGGL(radon_fwd, dim3(NT * NJBF), dim3(64, 4), 0, stream,
                           x, theta, out);
        return;
    }

    unsigned* xIh  = (unsigned*)((char*)d_ws + XIH_OFF);
    unsigned* xTIh = (unsigned*)((char*)d_ws + XTIH_OFF);
    int2*     bbox = (int2*)((char*)d_ws + BBOX_OFF);

    hipLaunchKernelGGL(prep_k, dim3(351), dim3(32, 8), 0, stream,
                       x, theta, xIh, xTIh, bbox);
    hipLaunchKernelGGL(radon_wv5, dim3(NT * NJB), dim3(256), 0, stream,
                       xIh, xTIh, theta, (const int4*)bbox, out);
}